// Round 2
// baseline (4884.449 us; speedup 1.0000x reference)
//
#include <hip/hip_runtime.h>
#include <math.h>

#define NN 50000
#define NE 400000
#define NG 512
#define EPS 1e-5f

typedef unsigned int u32;
typedef unsigned short u16;

__device__ __forceinline__ float b2f(u16 h) { return __uint_as_float(((u32)h) << 16); }
__device__ __forceinline__ u16 f2b(float f) {
    u32 x = __float_as_uint(f);
    u32 r = x + 0x7fffu + ((x >> 16) & 1u);
    return (u16)(r >> 16);
}
struct alignas(16) U16x8 { u16 s[8]; };
struct alignas(8) U16x4 { u16 s[4]; };

__device__ __forceinline__ u32 fenc(float f) {
    u32 u = __float_as_uint(f);
    return (u & 0x80000000u) ? ~u : (u | 0x80000000u);
}
__device__ __forceinline__ float fdec(u32 e) {
    u32 u = (e & 0x80000000u) ? (e ^ 0x80000000u) : ~e;
    return __uint_as_float(u);
}
__device__ __forceinline__ void f4add(float4& a, const float4 b) {
    a.x += b.x; a.y += b.y; a.z += b.z; a.w += b.w;
}

// ---------------- setup: fold rotation matrices into ee_W1 (fp32) ----------------
__global__ void setup_kernel(const float* __restrict__ ang_rot, const float* __restrict__ ang_ref,
                             const float* __restrict__ W1, float* __restrict__ RWrot,
                             float* __restrict__ RWref) {
    int c = threadIdx.x;  // 64
    for (int which = 0; which < 2; ++which) {
        const float* a = which ? ang_ref : ang_rot;
        float t = a[0], p = a[1], q = a[2];
        float ct = cosf(t), st = sinf(t);
        float cp = cosf(p), sp = sinf(p);
        float cq = cosf(q), sq = sinf(q);
        float Rt[3][3] = {{ct, -st, 0.f}, {st, ct, 0.f}, {0.f, 0.f, 1.f}};
        float Rp[3][3] = {{cp, 0.f, -sp}, {0.f, 1.f, 0.f}, {sp, 0.f, cp}};
        float Rq[3][3] = {{1.f, 0.f, 0.f}, {0.f, cq, -sq}, {0.f, sq, cq}};
        float Rtp[3][3], R[3][3];
        for (int i = 0; i < 3; ++i)
            for (int j = 0; j < 3; ++j) {
                float s = 0.f;
                for (int k = 0; k < 3; ++k) s += Rt[i][k] * Rp[k][j];
                Rtp[i][j] = s;
            }
        for (int i = 0; i < 3; ++i)
            for (int j = 0; j < 3; ++j) {
                float s = 0.f;
                for (int k = 0; k < 3; ++k) s += Rtp[i][k] * Rq[k][j];
                R[i][j] = s;
            }
        float sgn = which ? -1.f : 1.f;  // R_ref = -rotmat(angles_ref)
        float* RW = which ? RWref : RWrot;
        if (c < 64) {
            for (int j = 0; j < 3; ++j) {
                float s = 0.f;
                for (int m = 0; m < 3; ++m) s += sgn * R[j][m] * W1[m * 64 + c];
                RW[j * 64 + c] = s;  // RW = R @ W1  (3 x 64)
            }
        }
    }
}

// ---------------- embedding gather: fp32 table -> bf16 out ----------------
__global__ __launch_bounds__(256) void gather_emb_kernel(const int* __restrict__ ntype,
                                                         const float* __restrict__ emb,
                                                         u16* __restrict__ out, int n) {
    long i = (long)blockIdx.x * 256 + threadIdx.x;  // over n*8
    long e = i >> 3;
    if (e >= n) return;
    int c0 = (int)(i & 7) * 8;
    int t = ntype[e];
    float4 a = *(const float4*)&emb[(long)t * 64 + c0];
    float4 b = *(const float4*)&emb[(long)t * 64 + c0 + 4];
    U16x8 o;
    o.s[0] = f2b(a.x); o.s[1] = f2b(a.y); o.s[2] = f2b(a.z); o.s[3] = f2b(a.w);
    o.s[4] = f2b(b.x); o.s[5] = f2b(b.y); o.s[6] = f2b(b.z); o.s[7] = f2b(b.w);
    *(U16x8*)&out[e * 64 + c0] = o;
}

// ---------------- t1 = efeats @ (R@W1) + b1 -> bf16 ----------------
__global__ __launch_bounds__(256) void edge_in_kernel(const float* __restrict__ ef,
                                                      const float* __restrict__ RW,
                                                      const float* __restrict__ b1,
                                                      u16* __restrict__ out, int E) {
    long i = (long)blockIdx.x * 256 + threadIdx.x;  // over E*8
    long e = i >> 3;
    if (e >= E) return;
    int c0 = (int)(i & 7) * 8;
    float f0 = ef[e * 3 + 0], f1 = ef[e * 3 + 1], f2 = ef[e * 3 + 2];
    U16x8 o;
#pragma unroll
    for (int half = 0; half < 2; ++half) {
        int c = c0 + half * 4;
        float4 w0 = *(const float4*)&RW[0 * 64 + c];
        float4 w1 = *(const float4*)&RW[1 * 64 + c];
        float4 w2 = *(const float4*)&RW[2 * 64 + c];
        float4 bb = *(const float4*)&b1[c];
        o.s[half * 4 + 0] = f2b(bb.x + f0 * w0.x + f1 * w1.x + f2 * w2.x);
        o.s[half * 4 + 1] = f2b(bb.y + f0 * w0.y + f1 * w1.y + f2 * w2.y);
        o.s[half * 4 + 2] = f2b(bb.z + f0 * w0.z + f1 * w1.z + f2 * w2.z);
        o.s[half * 4 + 3] = f2b(bb.w + f0 * w0.w + f1 * w1.w + f2 * w2.w);
    }
    *(U16x8*)&out[e * 64 + c0] = o;
}

// ---------------- column stats: acc[c]=sum, acc[COLS+c]=sumsq (fp32 acc) ----------------
template <int COLS, bool XBF>
__global__ __launch_bounds__(256) void colstats_kernel(const void* __restrict__ xv, int rows,
                                                       float* __restrict__ acc) {
    constexpr int TPR = COLS / 8;
    constexpr int RPB = 256 / TPR;
    __shared__ float4 sA[256], sB[256], sC[256], sD[256];
    int tid = threadIdx.x;
    int c8 = tid % TPR;
    int rl = tid / TPR;
    float s[8], q[8];
#pragma unroll
    for (int j = 0; j < 8; ++j) { s[j] = 0.f; q[j] = 0.f; }
    for (long r = (long)blockIdx.x * RPB + rl; r < rows; r += (long)gridDim.x * RPB) {
        float v[8];
        if (XBF) {
            U16x8 t = *(const U16x8*)((const u16*)xv + r * COLS + c8 * 8);
#pragma unroll
            for (int j = 0; j < 8; ++j) v[j] = b2f(t.s[j]);
        } else {
            float4 a = *(const float4*)((const float*)xv + r * COLS + c8 * 8);
            float4 b = *(const float4*)((const float*)xv + r * COLS + c8 * 8 + 4);
            v[0] = a.x; v[1] = a.y; v[2] = a.z; v[3] = a.w;
            v[4] = b.x; v[5] = b.y; v[6] = b.z; v[7] = b.w;
        }
#pragma unroll
        for (int j = 0; j < 8; ++j) { s[j] += v[j]; q[j] += v[j] * v[j]; }
    }
    sA[tid] = make_float4(s[0], s[1], s[2], s[3]);
    sB[tid] = make_float4(s[4], s[5], s[6], s[7]);
    sC[tid] = make_float4(q[0], q[1], q[2], q[3]);
    sD[tid] = make_float4(q[4], q[5], q[6], q[7]);
    __syncthreads();
    for (int off = 128; off >= TPR; off >>= 1) {
        if (tid < off) {
            f4add(sA[tid], sA[tid + off]); f4add(sB[tid], sB[tid + off]);
            f4add(sC[tid], sC[tid + off]); f4add(sD[tid], sD[tid + off]);
        }
        __syncthreads();
    }
    if (tid < TPR) {
        int c = tid * 8;
        float4 a = sA[tid], b = sB[tid], cq = sC[tid], d = sD[tid];
        atomicAdd(&acc[c + 0], a.x); atomicAdd(&acc[c + 1], a.y);
        atomicAdd(&acc[c + 2], a.z); atomicAdd(&acc[c + 3], a.w);
        atomicAdd(&acc[c + 4], b.x); atomicAdd(&acc[c + 5], b.y);
        atomicAdd(&acc[c + 6], b.z); atomicAdd(&acc[c + 7], b.w);
        atomicAdd(&acc[COLS + c + 0], cq.x); atomicAdd(&acc[COLS + c + 1], cq.y);
        atomicAdd(&acc[COLS + c + 2], cq.z); atomicAdd(&acc[COLS + c + 3], cq.w);
        atomicAdd(&acc[COLS + c + 4], d.x); atomicAdd(&acc[COLS + c + 5], d.y);
        atomicAdd(&acc[COLS + c + 6], d.z); atomicAdd(&acc[COLS + c + 7], d.w);
    }
}

// ---------------- elementwise y = relu(bn(x)) [+= y], bf16 x/y ----------------
__global__ __launch_bounds__(256) void bn_act_kernel(const u16* __restrict__ x,
                                                     u16* __restrict__ y, long rows, int cols,
                                                     const float* __restrict__ acc,
                                                     const float* __restrict__ g,
                                                     const float* __restrict__ b, float inv_rows,
                                                     int accumulate) {
    long i = (long)blockIdx.x * 256 + threadIdx.x;
    long total8 = rows * (long)cols / 8;
    if (i >= total8) return;
    long base = i * 8;
    int c0 = (int)(base % cols);
    U16x8 xv = *(const U16x8*)&x[base];
    float r[8];
#pragma unroll
    for (int j = 0; j < 8; ++j) {
        int c = c0 + j;
        float mu = acc[c] * inv_rows;
        float var = acc[cols + c] * inv_rows - mu * mu;
        float al = g[c] * rsqrtf(fmaxf(var, 0.f) + EPS);
        float be = b[c] - mu * al;
        float o = al * b2f(xv.s[j]) + be;
        r[j] = fmaxf(o, 0.f);
    }
    if (accumulate) {
        U16x8 yv = *(const U16x8*)&y[base];
#pragma unroll
        for (int j = 0; j < 8; ++j) r[j] += b2f(yv.s[j]);
    }
    U16x8 o;
#pragma unroll
    for (int j = 0; j < 8; ++j) o.s[j] = f2b(r[j]);
    *(U16x8*)&y[base] = o;
}

// ---------------- generic tiled matmul: Y = preop(X) @ W (+bias)(+res) ----------------
// preop: 0 none, 1 bn, 2 bn+relu, 3 bn+prelu(scalar)
// XBF: X is bf16; RBF: res is bf16; OBF: Y is bf16 (else fp32)
template <int K, int COLS, bool XBF, bool RBF, bool OBF>
__global__ __launch_bounds__(256) void mm_kernel(const void* __restrict__ Xv,
                                                 const float* __restrict__ Wg,
                                                 const float* __restrict__ bias, const void* resv,
                                                 void* Yv, int rows, int preop,
                                                 const float* __restrict__ stats,
                                                 const float* __restrict__ g,
                                                 const float* __restrict__ b, float inv_rows,
                                                 const float* __restrict__ prelu, int prelu_idx) {
    constexpr int TPR = COLS / 4;
    constexpr int RPB = 256 / TPR;
    constexpr int XP = K + 4;  // padded LDS stride (bank spread)
    __shared__ float ws[K * COLS];
    __shared__ float xs[RPB * XP];
    __shared__ float al[K];
    __shared__ float be[K];
    const int tid = threadIdx.x;

    for (int i = tid; i < K * COLS; i += 256) ws[i] = Wg[i];
    if (preop) {
        for (int k = tid; k < K; k += 256) {
            float mu = stats[k] * inv_rows;
            float var = stats[K + k] * inv_rows - mu * mu;
            float a = g[k] * rsqrtf(fmaxf(var, 0.f) + EPS);
            al[k] = a;
            be[k] = b[k] - mu * a;
        }
    }
    __syncthreads();

    const long r0 = (long)blockIdx.x * RPB;
    float pa = (preop == 3) ? prelu[prelu_idx] : 0.f;
    constexpr int NC = RPB * K / 4;
    for (int i = tid; i < NC; i += 256) {
        int b4 = i * 4;
        int rl = b4 / K, k0 = b4 % K;
        long r = r0 + rl;
        float v[4];
        if (r < rows) {
            if (XBF) {
                U16x4 t = *(const U16x4*)((const u16*)Xv + r * K + k0);
#pragma unroll
                for (int j = 0; j < 4; ++j) v[j] = b2f(t.s[j]);
            } else {
                float4 t = *(const float4*)((const float*)Xv + r * K + k0);
                v[0] = t.x; v[1] = t.y; v[2] = t.z; v[3] = t.w;
            }
        } else {
#pragma unroll
            for (int j = 0; j < 4; ++j) v[j] = 0.f;
        }
        if (preop) {
#pragma unroll
            for (int j = 0; j < 4; ++j) {
                float xx = al[k0 + j] * v[j] + be[k0 + j];
                if (preop == 2) xx = fmaxf(xx, 0.f);
                else if (preop == 3) xx = (xx >= 0.f) ? xx : pa * xx;
                v[j] = xx;
            }
        }
        xs[rl * XP + k0 + 0] = v[0];
        xs[rl * XP + k0 + 1] = v[1];
        xs[rl * XP + k0 + 2] = v[2];
        xs[rl * XP + k0 + 3] = v[3];
    }
    __syncthreads();

    const int rl = tid / TPR;
    const int c0 = (tid % TPR) * 4;
    float4 acc = {0.f, 0.f, 0.f, 0.f};
#pragma unroll
    for (int k = 0; k < K; k += 4) {
        float4 xv = *(const float4*)&xs[rl * XP + k];
#pragma unroll
        for (int j = 0; j < 4; ++j) {
            float xj = (&xv.x)[j];
            float4 wv = *(const float4*)&ws[(k + j) * COLS + c0];
            acc.x += xj * wv.x; acc.y += xj * wv.y;
            acc.z += xj * wv.z; acc.w += xj * wv.w;
        }
    }
    long r = r0 + rl;
    if (r < rows) {
        if (bias) f4add(acc, *(const float4*)&bias[c0]);
        if (resv) {
            if (RBF) {
                U16x4 t = *(const U16x4*)((const u16*)resv + r * COLS + c0);
                acc.x += b2f(t.s[0]); acc.y += b2f(t.s[1]);
                acc.z += b2f(t.s[2]); acc.w += b2f(t.s[3]);
            } else {
                f4add(acc, *(const float4*)((const float*)resv + r * COLS + c0));
            }
        }
        if (OBF) {
            U16x4 o;
            o.s[0] = f2b(acc.x); o.s[1] = f2b(acc.y);
            o.s[2] = f2b(acc.z); o.s[3] = f2b(acc.w);
            *(U16x4*)((u16*)Yv + r * COLS + c0) = o;
        } else {
            *(float4*)((float*)Yv + r * COLS + c0) = acc;
        }
    }
}

// ---------------- EGAT: f = leaky(eh@Wfij + ni[src] + nj[dst]); e_att; segment max ----------------
template <int COLS, bool WRITE_F>
__global__ __launch_bounds__(256) void egat_fe_kernel(
    const u16* __restrict__ EH, const float* __restrict__ Wg, const u16* __restrict__ NI,
    const u16* __restrict__ NJ, const int* __restrict__ src, const int* __restrict__ dst,
    const float* __restrict__ attn, u16* __restrict__ Fout, float* __restrict__ eatt,
    u32* __restrict__ emax, int E) {
    constexpr int TPR8 = COLS / 8;
    constexpr int RPB = 256 / TPR8;
    constexpr int H = COLS / 64;
    constexpr int XP = 68;
    __shared__ float ws[64 * COLS];
    __shared__ float xs[RPB * XP];
    const int tid = threadIdx.x;
    for (int i = tid; i < 64 * COLS; i += 256) ws[i] = Wg[i];
    const long r0 = (long)blockIdx.x * RPB;
    constexpr int NC = RPB * 8;
    for (int i = tid; i < NC; i += 256) {
        int rl = i / 8, k0 = (i % 8) * 8;
        long r = r0 + rl;
        float v[8];
        if (r < E) {
            U16x8 t = *(const U16x8*)&EH[r * 64 + k0];
#pragma unroll
            for (int j = 0; j < 8; ++j) v[j] = b2f(t.s[j]);
        } else {
#pragma unroll
            for (int j = 0; j < 8; ++j) v[j] = 0.f;
        }
#pragma unroll
        for (int j = 0; j < 8; ++j) xs[rl * XP + k0 + j] = v[j];
    }
    __syncthreads();
    const int rl = tid / TPR8;
    const int c0 = (tid % TPR8) * 8;
    float acc[8];
#pragma unroll
    for (int j = 0; j < 8; ++j) acc[j] = 0.f;
    for (int k = 0; k < 64; k += 4) {
        float4 xv = *(const float4*)&xs[rl * XP + k];
#pragma unroll
        for (int kk = 0; kk < 4; ++kk) {
            float xj = (&xv.x)[kk];
            float4 w0 = *(const float4*)&ws[(k + kk) * COLS + c0];
            float4 w1 = *(const float4*)&ws[(k + kk) * COLS + c0 + 4];
            acc[0] += xj * w0.x; acc[1] += xj * w0.y; acc[2] += xj * w0.z; acc[3] += xj * w0.w;
            acc[4] += xj * w1.x; acc[5] += xj * w1.y; acc[6] += xj * w1.z; acc[7] += xj * w1.w;
        }
    }
    long e = r0 + rl;
    int h = c0 >> 6;
    float part = 0.f;
    int d = 0;
    if (e < E) {
        int s = src[e];
        d = dst[e];
        U16x8 ni8 = *(const U16x8*)&NI[(long)s * COLS + c0];
        U16x8 nj8 = *(const U16x8*)&NJ[(long)d * COLS + c0];
        float4 a0 = *(const float4*)&attn[h * 64 + (c0 & 63)];
        float4 a1 = *(const float4*)&attn[h * 64 + (c0 & 63) + 4];
        float av[8] = {a0.x, a0.y, a0.z, a0.w, a1.x, a1.y, a1.z, a1.w};
        U16x8 fo;
#pragma unroll
        for (int j = 0; j < 8; ++j) {
            float f = acc[j] + b2f(ni8.s[j]) + b2f(nj8.s[j]);
            f = (f >= 0.f) ? f : 0.01f * f;
            fo.s[j] = f2b(f);
            part += f * av[j];
        }
        if (WRITE_F) *(U16x8*)&Fout[e * COLS + c0] = fo;
    }
#pragma unroll
    for (int off = 1; off < 8; off <<= 1) part += __shfl_xor(part, off, 64);
    if (e < E && (tid & 7) == 0) {
        eatt[e * H + h] = part;
        atomicMax(&emax[(long)d * H + h], fenc(part));
    }
}

// ---------------- softmax numerator + denominator ----------------
__global__ __launch_bounds__(256) void edge_softmax_kernel(float* __restrict__ eatt,
                                                           const int* __restrict__ dst,
                                                           const u32* __restrict__ emax,
                                                           float* __restrict__ denom, long total,
                                                           int H) {
    long i = (long)blockIdx.x * 256 + threadIdx.x;
    if (i >= total) return;
    long e = i / H;
    int h = (int)(i - e * H);
    long idx = (long)dst[e] * H + h;
    float m = fdec(emax[idx]);
    float v = expf(eatt[i] - m);
    eatt[i] = v;
    atomicAdd(&denom[idx], v);
}

// ---------------- weighted segment-sum scatter ----------------
template <int COLS>
__global__ __launch_bounds__(256) void egat_scatter_kernel(
    const u16* __restrict__ nodeh, const float* __restrict__ ee, const float* __restrict__ denom,
    const int* __restrict__ src, const int* __restrict__ dst, float* __restrict__ hout, int E) {
    constexpr int RPB = 256 / COLS;
    constexpr int H = COLS / 64;
    int tid = threadIdx.x;
    long e = (long)blockIdx.x * RPB + tid / COLS;
    if (e >= E) return;
    int c = tid % COLS;
    int h = c >> 6;
    float a = ee[e * H + h] / denom[(long)dst[e] * H + h];
    float v = b2f(nodeh[(long)src[e] * COLS + c]) * a;
    atomicAdd(&hout[(long)dst[e] * COLS + c], v);
}

// ---------------- decoder tail: prelu(bn(t3)) @ Wout + bout -> pool by graph ----------------
__global__ __launch_bounds__(256) void decoder_out_kernel(
    const u16* __restrict__ t3, const float* __restrict__ stats, const float* __restrict__ g,
    const float* __restrict__ b, const float* __restrict__ prelu, const float* __restrict__ Wout,
    const float* __restrict__ bout, const int* __restrict__ gid, float* __restrict__ pool,
    int rows, float inv_rows) {
    int tid = threadIdx.x;
    long r = (long)blockIdx.x * 4 + (tid >> 6);
    if (r >= rows) return;
    int k = tid & 63;
    float mu = stats[k] * inv_rows;
    float var = stats[64 + k] * inv_rows - mu * mu;
    float al = g[k] * rsqrtf(fmaxf(var, 0.f) + EPS);
    float be = b[k] - mu * al;
    float a = prelu[3];
    float v = al * b2f(t3[r * 64 + k]) + be;
    v = (v >= 0.f) ? v : a * v;
    v *= Wout[k];
#pragma unroll
    for (int off = 1; off < 64; off <<= 1) v += __shfl_xor(v, off, 64);
    if (k == 0) atomicAdd(&pool[gid[r]], v + bout[0]);
}

// =====================================================================================
extern "C" void kernel_launch(void* const* d_in, const int* in_sizes, int n_in, void* d_out,
                              int out_size, void* d_ws, size_t ws_size, hipStream_t stream) {
    if (n_in < 57) return;
    // ---- inputs (setup_inputs dict order) ----
    const int* ntype = (const int*)d_in[0];
    const int* src = (const int*)d_in[1];
    const int* dst = (const int*)d_in[2];
    const int* gid = (const int*)d_in[3];
    const float* ang_rot = (const float*)d_in[4];
    const float* ang_ref = (const float*)d_in[5];
    const float* efeats = (const float*)d_in[6];
    const float* emb = (const float*)d_in[7];
    const float* enc_W = (const float*)d_in[8];
    const float* enc_b = (const float*)d_in[9];
    const float* ee_W1 = (const float*)d_in[10];
    const float* ee_b1 = (const float*)d_in[11];
    const float* ee_W2 = (const float*)d_in[12];
    const float* ee_b2 = (const float*)d_in[13];
    const float* enc_bn1_g = (const float*)d_in[14];
    const float* enc_bn1_b = (const float*)d_in[15];
    const float* enc_bn2_g = (const float*)d_in[16];
    const float* enc_bn2_b = (const float*)d_in[17];
    const float* ee_bn1_g = (const float*)d_in[18];
    const float* ee_bn1_b = (const float*)d_in[19];
    const float* ee_bn2_g = (const float*)d_in[20];
    const float* ee_bn2_b = (const float*)d_in[21];
    const float* l0_Wnode = (const float*)d_in[22];
    const float* l0_bnode = (const float*)d_in[23];
    const float* l0_Wni = (const float*)d_in[24];
    const float* l0_Wnj = (const float*)d_in[25];
    const float* l0_Wfij = (const float*)d_in[26];
    const float* l0_attn = (const float*)d_in[27];
    const float* l0_bnn_g = (const float*)d_in[28];
    const float* l0_bnn_b = (const float*)d_in[29];
    const float* l0_bne_g = (const float*)d_in[30];
    const float* l0_bne_b = (const float*)d_in[31];
    const float* l0_Wpn = (const float*)d_in[32];
    const float* l0_bpn = (const float*)d_in[33];
    const float* l0_Wpe = (const float*)d_in[34];
    const float* l0_bpe = (const float*)d_in[35];
    const float* l1_Wnode = (const float*)d_in[36];
    const float* l1_bnode = (const float*)d_in[37];
    const float* l1_Wni = (const float*)d_in[38];
    const float* l1_Wnj = (const float*)d_in[39];
    const float* l1_Wfij = (const float*)d_in[40];
    const float* l1_attn = (const float*)d_in[41];
    const float* l1_bnn_g = (const float*)d_in[42];
    const float* l1_bnn_b = (const float*)d_in[43];
    // d_in[44..45,48..49]: l1_bne_*, l1_Wpe, l1_bpe are dead (layer-1 edge output unused)
    const float* l1_Wpn = (const float*)d_in[46];
    const float* l1_bpn = (const float*)d_in[47];
    const float* dec_W = (const float*)d_in[50];
    const float* dec_b = (const float*)d_in[51];
    const float* dec_bn_g = (const float*)d_in[52];
    const float* dec_bn_b = (const float*)d_in[53];
    const float* dec_prelu = (const float*)d_in[54];
    const float* dec_Wout = (const float*)d_in[55];
    const float* dec_bout = (const float*)d_in[56];

    float* out = (float*)d_out;
    float* H1 = out;                     // N x 64 (fp32)
    float* H2 = out + (long)NN * 64;     // N x 64 (fp32)
    float* POOL = out + (long)NN * 128;  // G x 1 (fp32)

    // ---- workspace layout (byte-based, 256B aligned) ----
    char* base = (char*)d_ws;
    size_t off = 0;
    auto alloc = [&](size_t bytes) -> void* {
        off = (off + 255) & ~(size_t)255;
        void* p = base + off;
        off += bytes;
        return p;
    };
    u16* EH = (u16*)alloc((size_t)NE * 64 * 2);     // 51.2 MB
    u16* F128 = (u16*)alloc((size_t)NE * 128 * 2);  // 102.4 MB (aliases T1/T2, NX0/NT)
    float* EATT = (float*)alloc((size_t)NE * 2 * 4);
    u16* NX = (u16*)alloc((size_t)NN * 64 * 2);
    u16* NI = (u16*)alloc((size_t)NN * 128 * 2);
    u16* NJ = (u16*)alloc((size_t)NN * 128 * 2);
    u16* NHH = (u16*)alloc((size_t)NN * 128 * 2);
    char* zstart = base + ((off + 255) & ~(size_t)255);
    float* HOUT0 = (float*)alloc((size_t)NN * 128 * 4);
    float* HOUT1 = (float*)alloc((size_t)NN * 64 * 4);
    u32* EMAX0 = (u32*)alloc((size_t)NN * 2 * 4);
    float* DEN0 = (float*)alloc((size_t)NN * 2 * 4);
    u32* EMAX1 = (u32*)alloc((size_t)NN * 4);
    float* DEN1 = (float*)alloc((size_t)NN * 4);
    float* STATS = (float*)alloc((size_t)13 * 256 * 4);
    char* zend = base + off;
    float* RWrot = (float*)alloc(256 * 4);
    float* RWref = (float*)alloc(256 * 4);
    if (ws_size < off) return;  // diagnostic: clean fail instead of OOB fault

    // aliases
    u16* T1 = F128;                       // NE x 64 bf16
    u16* T2 = F128 + (size_t)NE * 64;     // NE x 64 bf16
    u16* NX0 = F128;                      // NN x 64 bf16 (node-enc temp)
    u16* NT = F128 + (size_t)NN * 64;     // NN x 64 bf16 (node-enc temp)
    u16* DT0 = NI;                        // NN x 64 bf16 (decoder temp)
    u16* DT1 = NJ;                        // NN x 64 bf16 (decoder temp)

    float* S_enc1 = STATS + 0 * 256;
    float* S_enc2 = STATS + 1 * 256;
    float* S_ee1r = STATS + 2 * 256;
    float* S_ee2r = STATS + 3 * 256;
    float* S_ee1f = STATS + 4 * 256;
    float* S_ee2f = STATS + 5 * 256;
    float* S_bnn0 = STATS + 6 * 256;
    float* S_bne0 = STATS + 7 * 256;
    float* S_bnn1 = STATS + 8 * 256;
    float* S_d0 = STATS + 9 * 256;
    float* S_d1 = STATS + 10 * 256;
    float* S_d2 = STATS + 11 * 256;
    float* S_d3 = STATS + 12 * 256;

    const float invN = 1.f / (float)NN;
    const float invE = 1.f / (float)NE;
    const int GS = 1280;

    // ---- per-call re-init ----
    hipMemsetAsync(zstart, 0, (size_t)(zend - zstart), stream);
    hipMemsetAsync(POOL, 0, (size_t)NG * 4, stream);

    setup_kernel<<<1, 64, 0, stream>>>(ang_rot, ang_ref, ee_W1, RWrot, RWref);

    // ---- node encoder ----
    gather_emb_kernel<<<(NN * 8 + 255) / 256, 256, 0, stream>>>(ntype, emb, NX0, NN);
    colstats_kernel<64, true><<<GS, 256, 0, stream>>>(NX0, NN, S_enc1);
    mm_kernel<64, 64, true, false, true><<<(NN + 15) / 16, 256, 0, stream>>>(
        NX0, enc_W, enc_b, nullptr, NT, NN, 2, S_enc1, enc_bn1_g, enc_bn1_b, invN, nullptr, 0);
    colstats_kernel<64, true><<<GS, 256, 0, stream>>>(NT, NN, S_enc2);
    bn_act_kernel<<<(NN * 8 + 255) / 256, 256, 0, stream>>>(NT, NX, NN, 64, S_enc2, enc_bn2_g,
                                                            enc_bn2_b, invN, 0);

    // ---- edge encoder (two rotation branches, summed into EH) ----
    for (int br = 0; br < 2; ++br) {
        const float* RW = br ? RWref : RWrot;
        float* S1 = br ? S_ee1f : S_ee1r;
        float* S2 = br ? S_ee2f : S_ee2r;
        edge_in_kernel<<<(NE * 8 + 255) / 256, 256, 0, stream>>>(efeats, RW, ee_b1, T1, NE);
        colstats_kernel<64, true><<<GS, 256, 0, stream>>>(T1, NE, S1);
        mm_kernel<64, 64, true, false, true><<<(NE + 15) / 16, 256, 0, stream>>>(
            T1, ee_W2, ee_b2, nullptr, T2, NE, 2, S1, ee_bn1_g, ee_bn1_b, invE, nullptr, 0);
        colstats_kernel<64, true><<<GS, 256, 0, stream>>>(T2, NE, S2);
        bn_act_kernel<<<(NE * 8 + 255) / 256, 256, 0, stream>>>(T2, EH, NE, 64, S2, ee_bn2_g,
                                                                ee_bn2_b, invE, br);
    }

    // ---- layer 0 (H=2) ----
    mm_kernel<64, 128, true, false, true><<<(NN + 7) / 8, 256, 0, stream>>>(
        NX, l0_Wni, nullptr, nullptr, NI, NN, 0, nullptr, nullptr, nullptr, 0.f, nullptr, 0);
    mm_kernel<64, 128, true, false, true><<<(NN + 7) / 8, 256, 0, stream>>>(
        NX, l0_Wnj, nullptr, nullptr, NJ, NN, 0, nullptr, nullptr, nullptr, 0.f, nullptr, 0);
    mm_kernel<64, 128, true, false, true><<<(NN + 7) / 8, 256, 0, stream>>>(
        NX, l0_Wnode, l0_bnode, nullptr, NHH, NN, 0, nullptr, nullptr, nullptr, 0.f, nullptr, 0);
    egat_fe_kernel<128, true><<<(NE + 15) / 16, 256, 0, stream>>>(EH, l0_Wfij, NI, NJ, src, dst,
                                                                  l0_attn, F128, EATT, EMAX0, NE);
    edge_softmax_kernel<<<((long)NE * 2 + 255) / 256, 256, 0, stream>>>(EATT, dst, EMAX0, DEN0,
                                                                        (long)NE * 2, 2);
    egat_scatter_kernel<128><<<(NE + 1) / 2, 256, 0, stream>>>(NHH, EATT, DEN0, src, dst, HOUT0,
                                                               NE);
    colstats_kernel<128, false><<<GS, 256, 0, stream>>>(HOUT0, NN, S_bnn0);
    colstats_kernel<128, true><<<GS, 256, 0, stream>>>(F128, NE, S_bne0);
    mm_kernel<128, 64, false, true, false><<<(NN + 15) / 16, 256, 0, stream>>>(
        HOUT0, l0_Wpn, l0_bpn, NX, H1, NN, 1, S_bnn0, l0_bnn_g, l0_bnn_b, invN, nullptr, 0);
    mm_kernel<128, 64, true, true, true><<<(NE + 15) / 16, 256, 0, stream>>>(
        F128, l0_Wpe, l0_bpe, EH, EH, NE, 1, S_bne0, l0_bne_g, l0_bne_b, invE, nullptr, 0);

    // ---- layer 1 (H=1; this layer's edge output is dead -> skipped) ----
    mm_kernel<64, 64, false, false, true><<<(NN + 15) / 16, 256, 0, stream>>>(
        H1, l1_Wni, nullptr, nullptr, NI, NN, 0, nullptr, nullptr, nullptr, 0.f, nullptr, 0);
    mm_kernel<64, 64, false, false, true><<<(NN + 15) / 16, 256, 0, stream>>>(
        H1, l1_Wnj, nullptr, nullptr, NJ, NN, 0, nullptr, nullptr, nullptr, 0.f, nullptr, 0);
    mm_kernel<64, 64, false, false, true><<<(NN + 15) / 16, 256, 0, stream>>>(
        H1, l1_Wnode, l1_bnode, nullptr, NHH, NN, 0, nullptr, nullptr, nullptr, 0.f, nullptr, 0);
    egat_fe_kernel<64, false><<<(NE + 31) / 32, 256, 0, stream>>>(EH, l1_Wfij, NI, NJ, src, dst,
                                                                  l1_attn, nullptr, EATT, EMAX1,
                                                                  NE);
    edge_softmax_kernel<<<(NE + 255) / 256, 256, 0, stream>>>(EATT, dst, EMAX1, DEN1, (long)NE, 1);
    egat_scatter_kernel<64><<<(NE + 3) / 4, 256, 0, stream>>>(NHH, EATT, DEN1, src, dst, HOUT1,
                                                              NE);
    colstats_kernel<64, false><<<GS, 256, 0, stream>>>(HOUT1, NN, S_bnn1);
    mm_kernel<64, 64, false, false, false><<<(NN + 15) / 16, 256, 0, stream>>>(
        HOUT1, l1_Wpn, l1_bpn, H1, H2, NN, 1, S_bnn1, l1_bnn_g, l1_bnn_b, invN, nullptr, 0);

    // ---- decoder ----
    mm_kernel<64, 64, false, false, true><<<(NN + 15) / 16, 256, 0, stream>>>(
        H2, dec_W, dec_b, nullptr, DT0, NN, 0, nullptr, nullptr, nullptr, 0.f, nullptr, 0);
    colstats_kernel<64, true><<<GS, 256, 0, stream>>>(DT0, NN, S_d0);
    mm_kernel<64, 64, true, false, true><<<(NN + 15) / 16, 256, 0, stream>>>(
        DT0, dec_W + 4096, dec_b + 64, nullptr, DT1, NN, 3, S_d0, dec_bn_g, dec_bn_b, invN,
        dec_prelu, 0);
    colstats_kernel<64, true><<<GS, 256, 0, stream>>>(DT1, NN, S_d1);
    mm_kernel<64, 64, true, false, true><<<(NN + 15) / 16, 256, 0, stream>>>(
        DT1, dec_W + 8192, dec_b + 128, nullptr, DT0, NN, 3, S_d1, dec_bn_g + 64, dec_bn_b + 64,
        invN, dec_prelu, 1);
    colstats_kernel<64, true><<<GS, 256, 0, stream>>>(DT0, NN, S_d2);
    mm_kernel<64, 64, true, false, true><<<(NN + 15) / 16, 256, 0, stream>>>(
        DT0, dec_W + 12288, dec_b + 192, nullptr, DT1, NN, 3, S_d2, dec_bn_g + 128,
        dec_bn_b + 128, invN, dec_prelu, 2);
    colstats_kernel<64, true><<<GS, 256, 0, stream>>>(DT1, NN, S_d3);
    decoder_out_kernel<<<(NN + 3) / 4, 256, 0, stream>>>(DT1, S_d3, dec_bn_g + 192,
                                                         dec_bn_b + 192, dec_prelu, dec_Wout,
                                                         dec_bout, gid, POOL, NN, invN);
}

// Round 3
// 1528.015 us; speedup vs baseline: 3.1966x; 3.1966x over previous
//
#include <hip/hip_runtime.h>
#include <math.h>

#define NN 50000
#define NE 400000
#define NG 512
#define EPS 1e-5f
#define NSLOT 64  // stats replica slots (atomic contention spreading)

typedef unsigned int u32;
typedef unsigned short u16;

__device__ __forceinline__ float b2f(u16 h) { return __uint_as_float(((u32)h) << 16); }
__device__ __forceinline__ u16 f2b(float f) {
    u32 x = __float_as_uint(f);
    u32 r = x + 0x7fffu + ((x >> 16) & 1u);
    return (u16)(r >> 16);
}
struct alignas(16) U16x8 { u16 s[8]; };
struct alignas(8) U16x4 { u16 s[4]; };

__device__ __forceinline__ u32 fenc(float f) {
    u32 u = __float_as_uint(f);
    return (u & 0x80000000u) ? ~u : (u | 0x80000000u);
}
__device__ __forceinline__ float fdec(u32 e) {
    u32 u = (e & 0x80000000u) ? (e ^ 0x80000000u) : ~e;
    return __uint_as_float(u);
}
__device__ __forceinline__ void f4add(float4& a, const float4 b) {
    a.x += b.x; a.y += b.y; a.z += b.z; a.w += b.w;
}

// ---------------- setup: fold rotation matrices into ee_W1 (fp32) ----------------
__global__ void setup_kernel(const float* __restrict__ ang_rot, const float* __restrict__ ang_ref,
                             const float* __restrict__ W1, float* __restrict__ RWrot,
                             float* __restrict__ RWref) {
    int c = threadIdx.x;  // 64
    for (int which = 0; which < 2; ++which) {
        const float* a = which ? ang_ref : ang_rot;
        float t = a[0], p = a[1], q = a[2];
        float ct = cosf(t), st = sinf(t);
        float cp = cosf(p), sp = sinf(p);
        float cq = cosf(q), sq = sinf(q);
        float Rt[3][3] = {{ct, -st, 0.f}, {st, ct, 0.f}, {0.f, 0.f, 1.f}};
        float Rp[3][3] = {{cp, 0.f, -sp}, {0.f, 1.f, 0.f}, {sp, 0.f, cp}};
        float Rq[3][3] = {{1.f, 0.f, 0.f}, {0.f, cq, -sq}, {0.f, sq, cq}};
        float Rtp[3][3], R[3][3];
        for (int i = 0; i < 3; ++i)
            for (int j = 0; j < 3; ++j) {
                float s = 0.f;
                for (int k = 0; k < 3; ++k) s += Rt[i][k] * Rp[k][j];
                Rtp[i][j] = s;
            }
        for (int i = 0; i < 3; ++i)
            for (int j = 0; j < 3; ++j) {
                float s = 0.f;
                for (int k = 0; k < 3; ++k) s += Rtp[i][k] * Rq[k][j];
                R[i][j] = s;
            }
        float sgn = which ? -1.f : 1.f;  // R_ref = -rotmat(angles_ref)
        float* RW = which ? RWref : RWrot;
        if (c < 64) {
            for (int j = 0; j < 3; ++j) {
                float s = 0.f;
                for (int m = 0; m < 3; ++m) s += sgn * R[j][m] * W1[m * 64 + c];
                RW[j * 64 + c] = s;  // RW = R @ W1  (3 x 64)
            }
        }
    }
}

// ---------------- embedding gather: fp32 table -> bf16 out ----------------
__global__ __launch_bounds__(256) void gather_emb_kernel(const int* __restrict__ ntype,
                                                         const float* __restrict__ emb,
                                                         u16* __restrict__ out, int n) {
    long i = (long)blockIdx.x * 256 + threadIdx.x;  // over n*8
    long e = i >> 3;
    if (e >= n) return;
    int c0 = (int)(i & 7) * 8;
    int t = ntype[e];
    float4 a = *(const float4*)&emb[(long)t * 64 + c0];
    float4 b = *(const float4*)&emb[(long)t * 64 + c0 + 4];
    U16x8 o;
    o.s[0] = f2b(a.x); o.s[1] = f2b(a.y); o.s[2] = f2b(a.z); o.s[3] = f2b(a.w);
    o.s[4] = f2b(b.x); o.s[5] = f2b(b.y); o.s[6] = f2b(b.z); o.s[7] = f2b(b.w);
    *(U16x8*)&out[e * 64 + c0] = o;
}

// ---------------- t1 = efeats @ (R@W1) + b1 -> bf16 ----------------
__global__ __launch_bounds__(256) void edge_in_kernel(const float* __restrict__ ef,
                                                      const float* __restrict__ RW,
                                                      const float* __restrict__ b1,
                                                      u16* __restrict__ out, int E) {
    long i = (long)blockIdx.x * 256 + threadIdx.x;  // over E*8
    long e = i >> 3;
    if (e >= E) return;
    int c0 = (int)(i & 7) * 8;
    float f0 = ef[e * 3 + 0], f1 = ef[e * 3 + 1], f2 = ef[e * 3 + 2];
    U16x8 o;
#pragma unroll
    for (int half = 0; half < 2; ++half) {
        int c = c0 + half * 4;
        float4 w0 = *(const float4*)&RW[0 * 64 + c];
        float4 w1 = *(const float4*)&RW[1 * 64 + c];
        float4 w2 = *(const float4*)&RW[2 * 64 + c];
        float4 bb = *(const float4*)&b1[c];
        o.s[half * 4 + 0] = f2b(bb.x + f0 * w0.x + f1 * w1.x + f2 * w2.x);
        o.s[half * 4 + 1] = f2b(bb.y + f0 * w0.y + f1 * w1.y + f2 * w2.y);
        o.s[half * 4 + 2] = f2b(bb.z + f0 * w0.z + f1 * w1.z + f2 * w2.z);
        o.s[half * 4 + 3] = f2b(bb.w + f0 * w0.w + f1 * w1.w + f2 * w2.w);
    }
    *(U16x8*)&out[e * 64 + c0] = o;
}

// ---------------- column stats -> replicated raw accumulators ----------------
// raw layout: NSLOT slots x 256 floats; slot[c]=sum, slot[COLS+c]=sumsq
template <int COLS, bool XBF>
__global__ __launch_bounds__(256) void colstats_kernel(const void* __restrict__ xv, int rows,
                                                       float* __restrict__ raw) {
    constexpr int TPR = COLS / 8;
    constexpr int RPB = 256 / TPR;
    __shared__ float4 sA[256], sB[256], sC[256], sD[256];
    int tid = threadIdx.x;
    int c8 = tid % TPR;
    int rl = tid / TPR;
    float s[8], q[8];
#pragma unroll
    for (int j = 0; j < 8; ++j) { s[j] = 0.f; q[j] = 0.f; }
    const long stride = (long)gridDim.x * RPB;
    long r = (long)blockIdx.x * RPB + rl;
    auto loadrow = [&](long rr, float* v) {
        if (XBF) {
            U16x8 t = *(const U16x8*)((const u16*)xv + rr * COLS + c8 * 8);
#pragma unroll
            for (int j = 0; j < 8; ++j) v[j] = b2f(t.s[j]);
        } else {
            float4 a = *(const float4*)((const float*)xv + rr * COLS + c8 * 8);
            float4 b = *(const float4*)((const float*)xv + rr * COLS + c8 * 8 + 4);
            v[0] = a.x; v[1] = a.y; v[2] = a.z; v[3] = a.w;
            v[4] = b.x; v[5] = b.y; v[6] = b.z; v[7] = b.w;
        }
    };
    for (; r + stride < rows; r += 2 * stride) {
        float v0[8], v1[8];
        loadrow(r, v0);
        loadrow(r + stride, v1);
#pragma unroll
        for (int j = 0; j < 8; ++j) {
            s[j] += v0[j] + v1[j];
            q[j] += v0[j] * v0[j] + v1[j] * v1[j];
        }
    }
    if (r < rows) {
        float v0[8];
        loadrow(r, v0);
#pragma unroll
        for (int j = 0; j < 8; ++j) { s[j] += v0[j]; q[j] += v0[j] * v0[j]; }
    }
    sA[tid] = make_float4(s[0], s[1], s[2], s[3]);
    sB[tid] = make_float4(s[4], s[5], s[6], s[7]);
    sC[tid] = make_float4(q[0], q[1], q[2], q[3]);
    sD[tid] = make_float4(q[4], q[5], q[6], q[7]);
    __syncthreads();
    for (int off = 128; off >= TPR; off >>= 1) {
        if (tid < off) {
            f4add(sA[tid], sA[tid + off]); f4add(sB[tid], sB[tid + off]);
            f4add(sC[tid], sC[tid + off]); f4add(sD[tid], sD[tid + off]);
        }
        __syncthreads();
    }
    if (tid < TPR) {
        float* slot = raw + (size_t)(blockIdx.x & (NSLOT - 1)) * 256;
        int c = tid * 8;
        float4 a = sA[tid], b = sB[tid], cq = sC[tid], d = sD[tid];
        atomicAdd(&slot[c + 0], a.x); atomicAdd(&slot[c + 1], a.y);
        atomicAdd(&slot[c + 2], a.z); atomicAdd(&slot[c + 3], a.w);
        atomicAdd(&slot[c + 4], b.x); atomicAdd(&slot[c + 5], b.y);
        atomicAdd(&slot[c + 6], b.z); atomicAdd(&slot[c + 7], b.w);
        atomicAdd(&slot[COLS + c + 0], cq.x); atomicAdd(&slot[COLS + c + 1], cq.y);
        atomicAdd(&slot[COLS + c + 2], cq.z); atomicAdd(&slot[COLS + c + 3], cq.w);
        atomicAdd(&slot[COLS + c + 4], d.x); atomicAdd(&slot[COLS + c + 5], d.y);
        atomicAdd(&slot[COLS + c + 6], d.z); atomicAdd(&slot[COLS + c + 7], d.w);
    }
}

// ---------------- reduce NSLOT replica slots -> final stats (2*COLS floats) ----------------
__global__ __launch_bounds__(256) void finalize_stats_kernel(const float* __restrict__ raw,
                                                             float* __restrict__ stats, int n) {
    int i = threadIdx.x;
    if (i >= n) return;
    float s = 0.f;
#pragma unroll
    for (int r = 0; r < NSLOT; ++r) s += raw[r * 256 + i];
    stats[i] = s;
}

// ---------------- elementwise y = relu(bn(x)) [+= y], bf16 x/y ----------------
__global__ __launch_bounds__(256) void bn_act_kernel(const u16* __restrict__ x,
                                                     u16* __restrict__ y, long rows, int cols,
                                                     const float* __restrict__ acc,
                                                     const float* __restrict__ g,
                                                     const float* __restrict__ b, float inv_rows,
                                                     int accumulate) {
    long i = (long)blockIdx.x * 256 + threadIdx.x;
    long total8 = rows * (long)cols / 8;
    if (i >= total8) return;
    long base = i * 8;
    int c0 = (int)(base % cols);
    U16x8 xv = *(const U16x8*)&x[base];
    float r[8];
#pragma unroll
    for (int j = 0; j < 8; ++j) {
        int c = c0 + j;
        float mu = acc[c] * inv_rows;
        float var = acc[cols + c] * inv_rows - mu * mu;
        float al = g[c] * rsqrtf(fmaxf(var, 0.f) + EPS);
        float be = b[c] - mu * al;
        float o = al * b2f(xv.s[j]) + be;
        r[j] = fmaxf(o, 0.f);
    }
    if (accumulate) {
        U16x8 yv = *(const U16x8*)&y[base];
#pragma unroll
        for (int j = 0; j < 8; ++j) r[j] += b2f(yv.s[j]);
    }
    U16x8 o;
#pragma unroll
    for (int j = 0; j < 8; ++j) o.s[j] = f2b(r[j]);
    *(U16x8*)&y[base] = o;
}

// ---------------- generic tiled matmul: Y = preop(X) @ W (+bias)(+res) ----------------
// preop: 0 none, 1 bn, 2 bn+relu, 3 bn+prelu(scalar)
// XBF: X is bf16; RBF: res is bf16; OBF: Y is bf16 (else fp32)
template <int K, int COLS, bool XBF, bool RBF, bool OBF>
__global__ __launch_bounds__(256) void mm_kernel(const void* __restrict__ Xv,
                                                 const float* __restrict__ Wg,
                                                 const float* __restrict__ bias, const void* resv,
                                                 void* Yv, int rows, int preop,
                                                 const float* __restrict__ stats,
                                                 const float* __restrict__ g,
                                                 const float* __restrict__ b, float inv_rows,
                                                 const float* __restrict__ prelu, int prelu_idx) {
    constexpr int TPR = COLS / 4;
    constexpr int RPB = 256 / TPR;
    constexpr int XP = K + 4;  // padded LDS stride (bank spread)
    __shared__ float ws[K * COLS];
    __shared__ float xs[RPB * XP];
    __shared__ float al[K];
    __shared__ float be[K];
    const int tid = threadIdx.x;

    for (int i = tid; i < K * COLS; i += 256) ws[i] = Wg[i];
    if (preop) {
        for (int k = tid; k < K; k += 256) {
            float mu = stats[k] * inv_rows;
            float var = stats[K + k] * inv_rows - mu * mu;
            float a = g[k] * rsqrtf(fmaxf(var, 0.f) + EPS);
            al[k] = a;
            be[k] = b[k] - mu * a;
        }
    }
    __syncthreads();

    const long r0 = (long)blockIdx.x * RPB;
    float pa = (preop == 3) ? prelu[prelu_idx] : 0.f;
    constexpr int NC = RPB * K / 4;
    for (int i = tid; i < NC; i += 256) {
        int b4 = i * 4;
        int rl = b4 / K, k0 = b4 % K;
        long r = r0 + rl;
        float v[4];
        if (r < rows) {
            if (XBF) {
                U16x4 t = *(const U16x4*)((const u16*)Xv + r * K + k0);
#pragma unroll
                for (int j = 0; j < 4; ++j) v[j] = b2f(t.s[j]);
            } else {
                float4 t = *(const float4*)((const float*)Xv + r * K + k0);
                v[0] = t.x; v[1] = t.y; v[2] = t.z; v[3] = t.w;
            }
        } else {
#pragma unroll
            for (int j = 0; j < 4; ++j) v[j] = 0.f;
        }
        if (preop) {
#pragma unroll
            for (int j = 0; j < 4; ++j) {
                float xx = al[k0 + j] * v[j] + be[k0 + j];
                if (preop == 2) xx = fmaxf(xx, 0.f);
                else if (preop == 3) xx = (xx >= 0.f) ? xx : pa * xx;
                v[j] = xx;
            }
        }
        xs[rl * XP + k0 + 0] = v[0];
        xs[rl * XP + k0 + 1] = v[1];
        xs[rl * XP + k0 + 2] = v[2];
        xs[rl * XP + k0 + 3] = v[3];
    }
    __syncthreads();

    const int rl = tid / TPR;
    const int c0 = (tid % TPR) * 4;
    float4 acc = {0.f, 0.f, 0.f, 0.f};
#pragma unroll
    for (int k = 0; k < K; k += 4) {
        float4 xv = *(const float4*)&xs[rl * XP + k];
#pragma unroll
        for (int j = 0; j < 4; ++j) {
            float xj = (&xv.x)[j];
            float4 wv = *(const float4*)&ws[(k + j) * COLS + c0];
            acc.x += xj * wv.x; acc.y += xj * wv.y;
            acc.z += xj * wv.z; acc.w += xj * wv.w;
        }
    }
    long r = r0 + rl;
    if (r < rows) {
        if (bias) f4add(acc, *(const float4*)&bias[c0]);
        if (resv) {
            if (RBF) {
                U16x4 t = *(const U16x4*)((const u16*)resv + r * COLS + c0);
                acc.x += b2f(t.s[0]); acc.y += b2f(t.s[1]);
                acc.z += b2f(t.s[2]); acc.w += b2f(t.s[3]);
            } else {
                f4add(acc, *(const float4*)((const float*)resv + r * COLS + c0));
            }
        }
        if (OBF) {
            U16x4 o;
            o.s[0] = f2b(acc.x); o.s[1] = f2b(acc.y);
            o.s[2] = f2b(acc.z); o.s[3] = f2b(acc.w);
            *(U16x4*)((u16*)Yv + r * COLS + c0) = o;
        } else {
            *(float4*)((float*)Yv + r * COLS + c0) = acc;
        }
    }
}

// ---------------- EGAT: f = leaky(eh@Wfij + ni[src] + nj[dst]); e_att; segment max ----------------
template <int COLS, bool WRITE_F>
__global__ __launch_bounds__(256) void egat_fe_kernel(
    const u16* __restrict__ EH, const float* __restrict__ Wg, const u16* __restrict__ NI,
    const u16* __restrict__ NJ, const int* __restrict__ src, const int* __restrict__ dst,
    const float* __restrict__ attn, u16* __restrict__ Fout, float* __restrict__ eatt,
    u32* __restrict__ emax, int E) {
    constexpr int TPR8 = COLS / 8;
    constexpr int RPB = 256 / TPR8;
    constexpr int H = COLS / 64;
    constexpr int XP = 68;
    __shared__ float ws[64 * COLS];
    __shared__ float xs[RPB * XP];
    const int tid = threadIdx.x;
    for (int i = tid; i < 64 * COLS; i += 256) ws[i] = Wg[i];
    const long r0 = (long)blockIdx.x * RPB;
    constexpr int NC = RPB * 8;
    for (int i = tid; i < NC; i += 256) {
        int rl = i / 8, k0 = (i % 8) * 8;
        long r = r0 + rl;
        float v[8];
        if (r < E) {
            U16x8 t = *(const U16x8*)&EH[r * 64 + k0];
#pragma unroll
            for (int j = 0; j < 8; ++j) v[j] = b2f(t.s[j]);
        } else {
#pragma unroll
            for (int j = 0; j < 8; ++j) v[j] = 0.f;
        }
#pragma unroll
        for (int j = 0; j < 8; ++j) xs[rl * XP + k0 + j] = v[j];
    }
    __syncthreads();
    const int rl = tid / TPR8;
    const int c0 = (tid % TPR8) * 8;
    float acc[8];
#pragma unroll
    for (int j = 0; j < 8; ++j) acc[j] = 0.f;
    for (int k = 0; k < 64; k += 4) {
        float4 xv = *(const float4*)&xs[rl * XP + k];
#pragma unroll
        for (int kk = 0; kk < 4; ++kk) {
            float xj = (&xv.x)[kk];
            float4 w0 = *(const float4*)&ws[(k + kk) * COLS + c0];
            float4 w1 = *(const float4*)&ws[(k + kk) * COLS + c0 + 4];
            acc[0] += xj * w0.x; acc[1] += xj * w0.y; acc[2] += xj * w0.z; acc[3] += xj * w0.w;
            acc[4] += xj * w1.x; acc[5] += xj * w1.y; acc[6] += xj * w1.z; acc[7] += xj * w1.w;
        }
    }
    long e = r0 + rl;
    int h = c0 >> 6;
    float part = 0.f;
    int d = 0;
    if (e < E) {
        int s = src[e];
        d = dst[e];
        U16x8 ni8 = *(const U16x8*)&NI[(long)s * COLS + c0];
        U16x8 nj8 = *(const U16x8*)&NJ[(long)d * COLS + c0];
        float4 a0 = *(const float4*)&attn[h * 64 + (c0 & 63)];
        float4 a1 = *(const float4*)&attn[h * 64 + (c0 & 63) + 4];
        float av[8] = {a0.x, a0.y, a0.z, a0.w, a1.x, a1.y, a1.z, a1.w};
        U16x8 fo;
#pragma unroll
        for (int j = 0; j < 8; ++j) {
            float f = acc[j] + b2f(ni8.s[j]) + b2f(nj8.s[j]);
            f = (f >= 0.f) ? f : 0.01f * f;
            fo.s[j] = f2b(f);
            part += f * av[j];
        }
        if (WRITE_F) *(U16x8*)&Fout[e * COLS + c0] = fo;
    }
#pragma unroll
    for (int off = 1; off < 8; off <<= 1) part += __shfl_xor(part, off, 64);
    if (e < E && (tid & 7) == 0) {
        eatt[e * H + h] = part;
        atomicMax(&emax[(long)d * H + h], fenc(part));
    }
}

// ---------------- softmax numerator + denominator ----------------
__global__ __launch_bounds__(256) void edge_softmax_kernel(float* __restrict__ eatt,
                                                           const int* __restrict__ dst,
                                                           const u32* __restrict__ emax,
                                                           float* __restrict__ denom, long total,
                                                           int H) {
    long i = (long)blockIdx.x * 256 + threadIdx.x;
    if (i >= total) return;
    long e = i / H;
    int h = (int)(i - e * H);
    long idx = (long)dst[e] * H + h;
    float m = fdec(emax[idx]);
    float v = expf(eatt[i] - m);
    eatt[i] = v;
    atomicAdd(&denom[idx], v);
}

// ---------------- weighted segment-sum scatter ----------------
template <int COLS>
__global__ __launch_bounds__(256) void egat_scatter_kernel(
    const u16* __restrict__ nodeh, const float* __restrict__ ee, const float* __restrict__ denom,
    const int* __restrict__ src, const int* __restrict__ dst, float* __restrict__ hout, int E) {
    constexpr int RPB = 256 / COLS;
    constexpr int H = COLS / 64;
    int tid = threadIdx.x;
    long e = (long)blockIdx.x * RPB + tid / COLS;
    if (e >= E) return;
    int c = tid % COLS;
    int h = c >> 6;
    float a = ee[e * H + h] / denom[(long)dst[e] * H + h];
    float v = b2f(nodeh[(long)src[e] * COLS + c]) * a;
    atomicAdd(&hout[(long)dst[e] * COLS + c], v);
}

// ---------------- decoder tail: prelu(bn(t3)) @ Wout + bout -> pool by graph ----------------
__global__ __launch_bounds__(256) void decoder_out_kernel(
    const u16* __restrict__ t3, const float* __restrict__ stats, const float* __restrict__ g,
    const float* __restrict__ b, const float* __restrict__ prelu, const float* __restrict__ Wout,
    const float* __restrict__ bout, const int* __restrict__ gid, float* __restrict__ pool,
    int rows, float inv_rows) {
    int tid = threadIdx.x;
    long r = (long)blockIdx.x * 4 + (tid >> 6);
    if (r >= rows) return;
    int k = tid & 63;
    float mu = stats[k] * inv_rows;
    float var = stats[64 + k] * inv_rows - mu * mu;
    float al = g[k] * rsqrtf(fmaxf(var, 0.f) + EPS);
    float be = b[k] - mu * al;
    float a = prelu[3];
    float v = al * b2f(t3[r * 64 + k]) + be;
    v = (v >= 0.f) ? v : a * v;
    v *= Wout[k];
#pragma unroll
    for (int off = 1; off < 64; off <<= 1) v += __shfl_xor(v, off, 64);
    if (k == 0) atomicAdd(&pool[gid[r]], v + bout[0]);
}

// =====================================================================================
extern "C" void kernel_launch(void* const* d_in, const int* in_sizes, int n_in, void* d_out,
                              int out_size, void* d_ws, size_t ws_size, hipStream_t stream) {
    if (n_in < 57) return;
    // ---- inputs (setup_inputs dict order) ----
    const int* ntype = (const int*)d_in[0];
    const int* src = (const int*)d_in[1];
    const int* dst = (const int*)d_in[2];
    const int* gid = (const int*)d_in[3];
    const float* ang_rot = (const float*)d_in[4];
    const float* ang_ref = (const float*)d_in[5];
    const float* efeats = (const float*)d_in[6];
    const float* emb = (const float*)d_in[7];
    const float* enc_W = (const float*)d_in[8];
    const float* enc_b = (const float*)d_in[9];
    const float* ee_W1 = (const float*)d_in[10];
    const float* ee_b1 = (const float*)d_in[11];
    const float* ee_W2 = (const float*)d_in[12];
    const float* ee_b2 = (const float*)d_in[13];
    const float* enc_bn1_g = (const float*)d_in[14];
    const float* enc_bn1_b = (const float*)d_in[15];
    const float* enc_bn2_g = (const float*)d_in[16];
    const float* enc_bn2_b = (const float*)d_in[17];
    const float* ee_bn1_g = (const float*)d_in[18];
    const float* ee_bn1_b = (const float*)d_in[19];
    const float* ee_bn2_g = (const float*)d_in[20];
    const float* ee_bn2_b = (const float*)d_in[21];
    const float* l0_Wnode = (const float*)d_in[22];
    const float* l0_bnode = (const float*)d_in[23];
    const float* l0_Wni = (const float*)d_in[24];
    const float* l0_Wnj = (const float*)d_in[25];
    const float* l0_Wfij = (const float*)d_in[26];
    const float* l0_attn = (const float*)d_in[27];
    const float* l0_bnn_g = (const float*)d_in[28];
    const float* l0_bnn_b = (const float*)d_in[29];
    const float* l0_bne_g = (const float*)d_in[30];
    const float* l0_bne_b = (const float*)d_in[31];
    const float* l0_Wpn = (const float*)d_in[32];
    const float* l0_bpn = (const float*)d_in[33];
    const float* l0_Wpe = (const float*)d_in[34];
    const float* l0_bpe = (const float*)d_in[35];
    const float* l1_Wnode = (const float*)d_in[36];
    const float* l1_bnode = (const float*)d_in[37];
    const float* l1_Wni = (const float*)d_in[38];
    const float* l1_Wnj = (const float*)d_in[39];
    const float* l1_Wfij = (const float*)d_in[40];
    const float* l1_attn = (const float*)d_in[41];
    const float* l1_bnn_g = (const float*)d_in[42];
    const float* l1_bnn_b = (const float*)d_in[43];
    // d_in[44..45,48..49]: l1_bne_*, l1_Wpe, l1_bpe are dead (layer-1 edge output unused)
    const float* l1_Wpn = (const float*)d_in[46];
    const float* l1_bpn = (const float*)d_in[47];
    const float* dec_W = (const float*)d_in[50];
    const float* dec_b = (const float*)d_in[51];
    const float* dec_bn_g = (const float*)d_in[52];
    const float* dec_bn_b = (const float*)d_in[53];
    const float* dec_prelu = (const float*)d_in[54];
    const float* dec_Wout = (const float*)d_in[55];
    const float* dec_bout = (const float*)d_in[56];

    float* out = (float*)d_out;
    float* H1 = out;                     // N x 64 (fp32)
    float* H2 = out + (long)NN * 64;     // N x 64 (fp32)
    float* POOL = out + (long)NN * 128;  // G x 1 (fp32)

    // ---- workspace layout (byte-based, 256B aligned) ----
    char* base = (char*)d_ws;
    size_t off = 0;
    auto alloc = [&](size_t bytes) -> void* {
        off = (off + 255) & ~(size_t)255;
        void* p = base + off;
        off += bytes;
        return p;
    };
    u16* EH = (u16*)alloc((size_t)NE * 64 * 2);     // 51.2 MB
    u16* F128 = (u16*)alloc((size_t)NE * 128 * 2);  // 102.4 MB (aliases T1/T2, NX0/NT)
    float* EATT = (float*)alloc((size_t)NE * 2 * 4);
    u16* NX = (u16*)alloc((size_t)NN * 64 * 2);
    u16* NI = (u16*)alloc((size_t)NN * 128 * 2);
    u16* NJ = (u16*)alloc((size_t)NN * 128 * 2);
    u16* NHH = (u16*)alloc((size_t)NN * 128 * 2);
    char* zstart = base + ((off + 255) & ~(size_t)255);
    float* HOUT0 = (float*)alloc((size_t)NN * 128 * 4);
    float* HOUT1 = (float*)alloc((size_t)NN * 64 * 4);
    u32* EMAX0 = (u32*)alloc((size_t)NN * 2 * 4);
    float* DEN0 = (float*)alloc((size_t)NN * 2 * 4);
    u32* EMAX1 = (u32*)alloc((size_t)NN * 4);
    float* DEN1 = (float*)alloc((size_t)NN * 4);
    float* STATS_RAW = (float*)alloc((size_t)13 * NSLOT * 256 * 4);  // replicated accumulators
    float* STATS = (float*)alloc((size_t)13 * 256 * 4);
    char* zend = base + off;
    float* RWrot = (float*)alloc(256 * 4);
    float* RWref = (float*)alloc(256 * 4);
    if (ws_size < off) return;  // diagnostic: clean fail instead of OOB fault

    // aliases
    u16* T1 = F128;                       // NE x 64 bf16
    u16* T2 = F128 + (size_t)NE * 64;     // NE x 64 bf16
    u16* NX0 = F128;                      // NN x 64 bf16 (node-enc temp)
    u16* NT = F128 + (size_t)NN * 64;     // NN x 64 bf16 (node-enc temp)
    u16* DT0 = NI;                        // NN x 64 bf16 (decoder temp)
    u16* DT1 = NJ;                        // NN x 64 bf16 (decoder temp)

    auto RAW = [&](int idx) { return STATS_RAW + (size_t)idx * NSLOT * 256; };
    float* S_enc1 = STATS + 0 * 256;
    float* S_enc2 = STATS + 1 * 256;
    float* S_ee1r = STATS + 2 * 256;
    float* S_ee2r = STATS + 3 * 256;
    float* S_ee1f = STATS + 4 * 256;
    float* S_ee2f = STATS + 5 * 256;
    float* S_bnn0 = STATS + 6 * 256;
    float* S_bne0 = STATS + 7 * 256;
    float* S_bnn1 = STATS + 8 * 256;
    float* S_d0 = STATS + 9 * 256;
    float* S_d1 = STATS + 10 * 256;
    float* S_d2 = STATS + 11 * 256;
    float* S_d3 = STATS + 12 * 256;

    const float invN = 1.f / (float)NN;
    const float invE = 1.f / (float)NE;
    const int GS = 640;  // colstats grid

    // ---- per-call re-init ----
    hipMemsetAsync(zstart, 0, (size_t)(zend - zstart), stream);
    hipMemsetAsync(POOL, 0, (size_t)NG * 4, stream);

    setup_kernel<<<1, 64, 0, stream>>>(ang_rot, ang_ref, ee_W1, RWrot, RWref);

    // ---- node encoder ----
    gather_emb_kernel<<<(NN * 8 + 255) / 256, 256, 0, stream>>>(ntype, emb, NX0, NN);
    colstats_kernel<64, true><<<GS, 256, 0, stream>>>(NX0, NN, RAW(0));
    finalize_stats_kernel<<<1, 256, 0, stream>>>(RAW(0), S_enc1, 128);
    mm_kernel<64, 64, true, false, true><<<(NN + 15) / 16, 256, 0, stream>>>(
        NX0, enc_W, enc_b, nullptr, NT, NN, 2, S_enc1, enc_bn1_g, enc_bn1_b, invN, nullptr, 0);
    colstats_kernel<64, true><<<GS, 256, 0, stream>>>(NT, NN, RAW(1));
    finalize_stats_kernel<<<1, 256, 0, stream>>>(RAW(1), S_enc2, 128);
    bn_act_kernel<<<(NN * 8 + 255) / 256, 256, 0, stream>>>(NT, NX, NN, 64, S_enc2, enc_bn2_g,
                                                            enc_bn2_b, invN, 0);

    // ---- edge encoder (two rotation branches, summed into EH) ----
    for (int br = 0; br < 2; ++br) {
        const float* RW = br ? RWref : RWrot;
        float* S1 = br ? S_ee1f : S_ee1r;
        float* S2 = br ? S_ee2f : S_ee2r;
        int r1 = br ? 4 : 2, r2 = br ? 5 : 3;
        edge_in_kernel<<<(NE * 8 + 255) / 256, 256, 0, stream>>>(efeats, RW, ee_b1, T1, NE);
        colstats_kernel<64, true><<<GS, 256, 0, stream>>>(T1, NE, RAW(r1));
        finalize_stats_kernel<<<1, 256, 0, stream>>>(RAW(r1), S1, 128);
        mm_kernel<64, 64, true, false, true><<<(NE + 15) / 16, 256, 0, stream>>>(
            T1, ee_W2, ee_b2, nullptr, T2, NE, 2, S1, ee_bn1_g, ee_bn1_b, invE, nullptr, 0);
        colstats_kernel<64, true><<<GS, 256, 0, stream>>>(T2, NE, RAW(r2));
        finalize_stats_kernel<<<1, 256, 0, stream>>>(RAW(r2), S2, 128);
        bn_act_kernel<<<(NE * 8 + 255) / 256, 256, 0, stream>>>(T2, EH, NE, 64, S2, ee_bn2_g,
                                                                ee_bn2_b, invE, br);
    }

    // ---- layer 0 (H=2) ----
    mm_kernel<64, 128, true, false, true><<<(NN + 7) / 8, 256, 0, stream>>>(
        NX, l0_Wni, nullptr, nullptr, NI, NN, 0, nullptr, nullptr, nullptr, 0.f, nullptr, 0);
    mm_kernel<64, 128, true, false, true><<<(NN + 7) / 8, 256, 0, stream>>>(
        NX, l0_Wnj, nullptr, nullptr, NJ, NN, 0, nullptr, nullptr, nullptr, 0.f, nullptr, 0);
    mm_kernel<64, 128, true, false, true><<<(NN + 7) / 8, 256, 0, stream>>>(
        NX, l0_Wnode, l0_bnode, nullptr, NHH, NN, 0, nullptr, nullptr, nullptr, 0.f, nullptr, 0);
    egat_fe_kernel<128, true><<<(NE + 15) / 16, 256, 0, stream>>>(EH, l0_Wfij, NI, NJ, src, dst,
                                                                  l0_attn, F128, EATT, EMAX0, NE);
    edge_softmax_kernel<<<((long)NE * 2 + 255) / 256, 256, 0, stream>>>(EATT, dst, EMAX0, DEN0,
                                                                        (long)NE * 2, 2);
    egat_scatter_kernel<128><<<(NE + 1) / 2, 256, 0, stream>>>(NHH, EATT, DEN0, src, dst, HOUT0,
                                                               NE);
    colstats_kernel<128, false><<<GS, 256, 0, stream>>>(HOUT0, NN, RAW(6));
    finalize_stats_kernel<<<1, 256, 0, stream>>>(RAW(6), S_bnn0, 256);
    colstats_kernel<128, true><<<GS, 256, 0, stream>>>(F128, NE, RAW(7));
    finalize_stats_kernel<<<1, 256, 0, stream>>>(RAW(7), S_bne0, 256);
    mm_kernel<128, 64, false, true, false><<<(NN + 15) / 16, 256, 0, stream>>>(
        HOUT0, l0_Wpn, l0_bpn, NX, H1, NN, 1, S_bnn0, l0_bnn_g, l0_bnn_b, invN, nullptr, 0);
    mm_kernel<128, 64, true, true, true><<<(NE + 15) / 16, 256, 0, stream>>>(
        F128, l0_Wpe, l0_bpe, EH, EH, NE, 1, S_bne0, l0_bne_g, l0_bne_b, invE, nullptr, 0);

    // ---- layer 1 (H=1; this layer's edge output is dead -> skipped) ----
    mm_kernel<64, 64, false, false, true><<<(NN + 15) / 16, 256, 0, stream>>>(
        H1, l1_Wni, nullptr, nullptr, NI, NN, 0, nullptr, nullptr, nullptr, 0.f, nullptr, 0);
    mm_kernel<64, 64, false, false, true><<<(NN + 15) / 16, 256, 0, stream>>>(
        H1, l1_Wnj, nullptr, nullptr, NJ, NN, 0, nullptr, nullptr, nullptr, 0.f, nullptr, 0);
    mm_kernel<64, 64, false, false, true><<<(NN + 15) / 16, 256, 0, stream>>>(
        H1, l1_Wnode, l1_bnode, nullptr, NHH, NN, 0, nullptr, nullptr, nullptr, 0.f, nullptr, 0);
    egat_fe_kernel<64, false><<<(NE + 31) / 32, 256, 0, stream>>>(EH, l1_Wfij, NI, NJ, src, dst,
                                                                  l1_attn, nullptr, EATT, EMAX1,
                                                                  NE);
    edge_softmax_kernel<<<(NE + 255) / 256, 256, 0, stream>>>(EATT, dst, EMAX1, DEN1, (long)NE, 1);
    egat_scatter_kernel<64><<<(NE + 3) / 4, 256, 0, stream>>>(NHH, EATT, DEN1, src, dst, HOUT1,
                                                              NE);
    colstats_kernel<64, false><<<GS, 256, 0, stream>>>(HOUT1, NN, RAW(8));
    finalize_stats_kernel<<<1, 256, 0, stream>>>(RAW(8), S_bnn1, 128);
    mm_kernel<64, 64, false, false, false><<<(NN + 15) / 16, 256, 0, stream>>>(
        HOUT1, l1_Wpn, l1_bpn, H1, H2, NN, 1, S_bnn1, l1_bnn_g, l1_bnn_b, invN, nullptr, 0);

    // ---- decoder ----
    mm_kernel<64, 64, false, false, true><<<(NN + 15) / 16, 256, 0, stream>>>(
        H2, dec_W, dec_b, nullptr, DT0, NN, 0, nullptr, nullptr, nullptr, 0.f, nullptr, 0);
    colstats_kernel<64, true><<<GS, 256, 0, stream>>>(DT0, NN, RAW(9));
    finalize_stats_kernel<<<1, 256, 0, stream>>>(RAW(9), S_d0, 128);
    mm_kernel<64, 64, true, false, true><<<(NN + 15) / 16, 256, 0, stream>>>(
        DT0, dec_W + 4096, dec_b + 64, nullptr, DT1, NN, 3, S_d0, dec_bn_g, dec_bn_b, invN,
        dec_prelu, 0);
    colstats_kernel<64, true><<<GS, 256, 0, stream>>>(DT1, NN, RAW(10));
    finalize_stats_kernel<<<1, 256, 0, stream>>>(RAW(10), S_d1, 128);
    mm_kernel<64, 64, true, false, true><<<(NN + 15) / 16, 256, 0, stream>>>(
        DT1, dec_W + 8192, dec_b + 128, nullptr, DT0, NN, 3, S_d1, dec_bn_g + 64, dec_bn_b + 64,
        invN, dec_prelu, 1);
    colstats_kernel<64, true><<<GS, 256, 0, stream>>>(DT0, NN, RAW(11));
    finalize_stats_kernel<<<1, 256, 0, stream>>>(RAW(11), S_d2, 128);
    mm_kernel<64, 64, true, false, true><<<(NN + 15) / 16, 256, 0, stream>>>(
        DT0, dec_W + 12288, dec_b + 192, nullptr, DT1, NN, 3, S_d2, dec_bn_g + 128,
        dec_bn_b + 128, invN, dec_prelu, 2);
    colstats_kernel<64, true><<<GS, 256, 0, stream>>>(DT1, NN, RAW(12));
    finalize_stats_kernel<<<1, 256, 0, stream>>>(RAW(12), S_d3, 128);
    decoder_out_kernel<<<(NN + 3) / 4, 256, 0, stream>>>(DT1, S_d3, dec_bn_g + 192,
                                                         dec_bn_b + 192, dec_prelu, dec_Wout,
                                                         dec_bout, gid, POOL, NN, invN);
}